// Round 6
// baseline (126.842 us; speedup 1.0000x reference)
//
#include <hip/hip_runtime.h>

// CausalSelfAttention: B=4 T=2048 D=768 NH=12 DH=64, fp32 in/out, bf16 MFMA compute.
// v6: GEMM moves to BK=32 dbuf (32 KB LDS) + launch_bounds(256,4) -> 4 blocks/CU
// (16-wave tier) for cross-block latency hiding; new 64B-row XOR swizzle
// byte^=((row>>1)&3)<<4 on both DMA source and ds_read. Attn: LDS shrunk to true
// 32 KB + per-n softmax restructure (one live f32x16) + launch_bounds(256,4).

#define B_ 4
#define T_ 2048
#define D_ 768
#define NH_ 12
#define DH_ 64
#define M_ (B_ * T_)  // 8192

typedef __attribute__((ext_vector_type(8))) short bf16x8;    // 8 bf16 = 4 VGPRs
typedef __attribute__((ext_vector_type(4))) float f32x4;
typedef __attribute__((ext_vector_type(16))) float f32x16;
typedef __attribute__((ext_vector_type(4))) unsigned int u32x4;

__device__ __forceinline__ unsigned short f2bf(float f) {
  unsigned int u = __builtin_bit_cast(unsigned int, f);
  u += 0x7FFFu + ((u >> 16) & 1u);  // RNE
  return (unsigned short)(u >> 16);
}

__device__ __forceinline__ void async16(const void* g, void* l) {
  // global->LDS DMA, 16B/lane; LDS dest = wave-uniform base + lane*16 (m97/m104)
  __builtin_amdgcn_global_load_lds(
      (const __attribute__((address_space(1))) unsigned int*)g,
      (__attribute__((address_space(3))) unsigned int*)l, 16, 0, 0);
}

// ---------------------------------------------------------------- cvt fp32->bf16
__global__ void cvt_kernel(const float* __restrict__ x, const float* __restrict__ wq,
                           const float* __restrict__ wk, const float* __restrict__ wv,
                           const float* __restrict__ wo,
                           unsigned short* __restrict__ xb, unsigned short* __restrict__ wqb,
                           unsigned short* __restrict__ wkb, unsigned short* __restrict__ wvb,
                           unsigned short* __restrict__ wob) {
  const float* src; unsigned short* dst; int n4;
  switch (blockIdx.y) {
    case 0: src = x;  dst = xb;  n4 = M_ * D_ / 4; break;
    case 1: src = wq; dst = wqb; n4 = D_ * D_ / 4; break;
    case 2: src = wk; dst = wkb; n4 = D_ * D_ / 4; break;
    case 3: src = wv; dst = wvb; n4 = D_ * D_ / 4; break;
    default: src = wo; dst = wob; n4 = D_ * D_ / 4; break;
  }
  int stride = gridDim.x * blockDim.x;
  for (int i = blockIdx.x * blockDim.x + threadIdx.x; i < n4; i += stride) {
    float4 v = ((const float4*)src)[i];
    ushort4 o;
    o.x = f2bf(v.x); o.y = f2bf(v.y); o.z = f2bf(v.z); o.w = f2bf(v.w);
    ((ushort4*)dst)[i] = o;
  }
}

// ---------------------------------------------------------------- bf16 GEMM (B^T input)
// C[m][n] = (sum_k A[m][k]*W[n][k] + bias[n]) * scale.  128x128 tile, BK=32, 4 waves,
// double-buffered (32 KB LDS total) -> 4 blocks/CU at the 16-wave VGPR tier.
// 64B LDS rows; involution swizzle byte^=((row>>1)&3)<<4 (elem^=((row>>1)&3)<<3 at
// the global source) spreads 8 rows over 8 banks on ds_read_b128 (2-way free).
// mode: 0 = f32 [M][N], 1 = bf16 [M][N], 2 = bf16 V^T [(b*NH+h)*DH+d][t]
__global__ __launch_bounds__(256, 4) void gemm_kernel(
    const unsigned short* __restrict__ A,
    const unsigned short* __restrict__ W0, const unsigned short* __restrict__ W1,
    const unsigned short* __restrict__ W2,
    const float* __restrict__ bias0, const float* __restrict__ bias1,
    const float* __restrict__ bias2,
    void* out0, void* out1, void* out2,
    float s0, float s1, float s2,
    int M, int N, int K, int qkv) {
  __shared__ __align__(16) unsigned short As[2][128 * 32];
  __shared__ __align__(16) unsigned short Bs[2][128 * 32];

  int bid = blockIdx.x;
  int xcd = bid & 7, g = bid >> 3;
  int mt, nt, y;
  if (qkv) { mt = xcd + ((g / 18) << 3); int sub = g % 18; y = sub / 6; nt = sub % 6; }
  else     { mt = xcd + ((g / 6) << 3);  nt = g % 6; y = 0; }

  const unsigned short* W = y == 0 ? W0 : (y == 1 ? W1 : W2);
  const float* bias = y == 0 ? bias0 : (y == 1 ? bias1 : bias2);
  void* outp = y == 0 ? out0 : (y == 1 ? out1 : out2);
  float scl = y == 0 ? s0 : (y == 1 ? s1 : s2);
  int mode = qkv ? ((y == 2) ? 2 : 1) : 0;

  int tid = threadIdx.x, lane = tid & 63, w = tid >> 6;
  int l15 = lane & 15, l4 = lane >> 4;
  int wr = w >> 1, wc = w & 1;

  int m0 = mt << 7;
  int n0 = nt << 7;

  f32x4 acc[4][4] = {};

  // staging: 8 chunks of 1KB per 128x32 tile; wave w owns chunks {w, w+4}
  int sRow[2], sCol[2];
#pragma unroll
  for (int c = 0; c < 2; ++c) {
    int chunk = c * 4 + w;
    int row = chunk * 16 + (lane >> 2);
    int colE = (lane & 3) * 8;
    sRow[c] = row;
    sCol[c] = colE ^ (((row >> 1) & 3) << 3);   // pre-swizzle source column (elems)
  }

  // fragment read offsets (bytes) within one 8KB buffer
  int aoff[4], boff[4];
#pragma unroll
  for (int m = 0; m < 4; ++m) {
    int row = wr * 64 + m * 16 + l15;
    aoff[m] = row * 64 + ((l4 * 16) ^ (((row >> 1) & 3) << 4));
  }
#pragma unroll
  for (int n = 0; n < 4; ++n) {
    int row = wc * 64 + n * 16 + l15;
    boff[n] = row * 64 + ((l4 * 16) ^ (((row >> 1) & 3) << 4));
  }

  // prologue: issue tile 0 into buf 0
#pragma unroll
  for (int c = 0; c < 2; ++c) {
    async16(A + (size_t)(m0 + sRow[c]) * K + sCol[c], (char*)As[0] + (c * 4 + w) * 1024);
    async16(W + (size_t)(n0 + sRow[c]) * K + sCol[c], (char*)Bs[0] + (c * 4 + w) * 1024);
  }

  int nkt = K >> 5;   // 24 steps at K=768
#pragma unroll 1
  for (int t = 0; t < nkt; ++t) {
    int cur = t & 1;
    __syncthreads();   // drains tile-t DMAs (vmcnt(0)) + syncs buffer reuse
    if (t + 1 < nkt) {
      int kt1 = (t + 1) << 5;
#pragma unroll
      for (int c = 0; c < 2; ++c) {
        async16(A + (size_t)(m0 + sRow[c]) * K + kt1 + sCol[c],
                (char*)As[cur ^ 1] + (c * 4 + w) * 1024);
        async16(W + (size_t)(n0 + sRow[c]) * K + kt1 + sCol[c],
                (char*)Bs[cur ^ 1] + (c * 4 + w) * 1024);
      }
    }
    bf16x8 af[4], bfr[4];
#pragma unroll
    for (int m = 0; m < 4; ++m) af[m] = *(const bf16x8*)((const char*)As[cur] + aoff[m]);
#pragma unroll
    for (int n = 0; n < 4; ++n) bfr[n] = *(const bf16x8*)((const char*)Bs[cur] + boff[n]);
#pragma unroll
    for (int m = 0; m < 4; ++m)
#pragma unroll
      for (int n = 0; n < 4; ++n)
        acc[m][n] = __builtin_amdgcn_mfma_f32_16x16x32_bf16(af[m], bfr[n], acc[m][n], 0, 0, 0);
  }

  if (mode == 2) {
    // V^T epilogue: out[((b*NH+h)*DH + d)*T + t], 4 consecutive t per 8B store
#pragma unroll
    for (int n = 0; n < 4; ++n) {
      int col = n0 + wc * 64 + n * 16 + l15;   // = h*DH + d
      float bv = bias[col];
      int h = col >> 6, d = col & 63;
#pragma unroll
      for (int m = 0; m < 4; ++m) {
        int rbase = m0 + wr * 64 + m * 16 + l4 * 4;  // = b*T + t
        int bb = rbase >> 11, t = rbase & (T_ - 1);
        ushort4 o;
        o.x = f2bf(acc[m][n][0] + bv);
        o.y = f2bf(acc[m][n][1] + bv);
        o.z = f2bf(acc[m][n][2] + bv);
        o.w = f2bf(acc[m][n][3] + bv);
        *(ushort4*)((unsigned short*)outp + ((size_t)(bb * NH_ + h) * DH_ + d) * T_ + t) = o;
      }
    }
  } else {
#pragma unroll
    for (int n = 0; n < 4; ++n) {
      int col = n0 + wc * 64 + n * 16 + l15;
      float bv = bias[col];
#pragma unroll
      for (int m = 0; m < 4; ++m) {
        int rbase = m0 + wr * 64 + m * 16 + l4 * 4;
#pragma unroll
        for (int r = 0; r < 4; ++r) {
          float v = (acc[m][n][r] + bv) * scl;
          size_t idx = (size_t)(rbase + r) * N + col;
          if (mode == 1) ((unsigned short*)outp)[idx] = f2bf(v);
          else           ((float*)outp)[idx] = v;
        }
      }
    }
  }
}

// ---------------------------------------------------------------- flash attention v6
// Block = one q-tile of 128 rows; 4 waves x 32 q-rows; 32x32x16 bf16 MFMA.
// Swapped QK^T (S^T = mfma(K,Q)); raw-exp2 softmax; P in registers via
// v_cvt_pk_bf16_f32 + v_permlane32_swap_b32. Per-n processing keeps one f32x16
// live -> fits the 16-wave VGPR tier (launch_bounds(256,4)); LDS exactly 32 KB
// (K0=0,K1=8192,V0=16384,V1=24576) -> up to 4 blocks/CU for cross-block overlap.
__global__ __launch_bounds__(256, 4) void attn_kernel(
    const unsigned short* __restrict__ Q, const unsigned short* __restrict__ Kg,
    const unsigned short* __restrict__ VT, unsigned short* __restrict__ Z) {
  __shared__ __align__(16) char lds[32768];

  int tid = threadIdx.x, lane = tid & 63, w = tid >> 6;
  int l31 = lane & 31, hi = lane >> 5;
  int bid = blockIdx.x;
  int xcd = bid & 7, g = bid >> 3;       // per XCD: 96 blocks = 16 qt x 6 heads
  int qt = 15 - g / 6;                   // descending qt: big blocks dispatch first (LPT)
  int bh = xcd + (g % 6) * 8;
  int b = bh / NH_, h = bh % NH_;
  int q0 = qt * 128;
  int qrow = q0 + w * 32 + l31;

  const unsigned short* Qb = Q + (size_t)(b * T_) * D_ + h * DH_;
  const unsigned short* Kb = Kg + (size_t)(b * T_) * D_ + h * DH_;
  const unsigned short* VTb = VT + (size_t)(b * NH_ + h) * DH_ * T_;

  // Q B-frags: qf[s] holds Q[qrow][16s + 8hi .. +8)
  bf16x8 qf[4];
#pragma unroll
  for (int s = 0; s < 4; ++s)
    qf[s] = *(const bf16x8*)(Qb + (size_t)qrow * D_ + s * 16 + hi * 8);

  // staging geometry (per-lane global source pre-swizzled; LDS dest linear)
  int sRow[2], sCol[2];
#pragma unroll
  for (int c = 0; c < 2; ++c) {
    int pos = ((c * 4 + w) * 64 + lane) * 8;
    int row = pos >> 6, colE = pos & 63;
    sRow[c] = row;
    sCol[c] = colE ^ ((row & 7) << 3);
  }

  // K/V fragment offsets within one 8KB buffer: half n/dt (32 rows), k-slice s (16)
  int koff[2][4];
#pragma unroll
  for (int n = 0; n < 2; ++n)
#pragma unroll
    for (int s = 0; s < 4; ++s) {
      int row = n * 32 + l31;
      koff[n][s] = row * 128 + ((s * 32 + hi * 16) ^ ((row & 7) << 4));
    }

  f32x16 zt[2] = {};
  float l_run = 0.f;
  int ntiles = 2 * qt + 2;

  // prologue: stage tile 0 -> K0/V0
#pragma unroll
  for (int c = 0; c < 2; ++c) {
    async16(Kb + (size_t)sRow[c] * D_ + sCol[c], lds + 0 + (c * 4 + w) * 1024);
    async16(VTb + (size_t)sRow[c] * T_ + sCol[c], lds + 16384 + (c * 4 + w) * 1024);
  }

#define ATTN_TILE(KCUR, VCUR, KNXT, VNXT)                                              \
  do {                                                                                 \
    __syncthreads(); /* drains tile-t DMAs; closes reads of the nxt buffers */         \
    if (t + 1 < ntiles) {                                                              \
      int kv1 = (t + 1) * 64;                                                          \
      _Pragma("unroll") for (int c = 0; c < 2; ++c) {                                  \
        async16(Kb + (size_t)(kv1 + sRow[c]) * D_ + sCol[c],                           \
                lds + KNXT + (c * 4 + w) * 1024);                                      \
        async16(VTb + (size_t)sRow[c] * T_ + kv1 + sCol[c],                            \
                lds + VNXT + (c * 4 + w) * 1024);                                      \
      }                                                                                \
    }                                                                                  \
    bf16x8 pb[4];                                                                      \
    _Pragma("unroll") for (int n = 0; n < 2; ++n) {                                    \
      f32x16 a = {};                                                                   \
      __builtin_amdgcn_s_setprio(1);                                                   \
      _Pragma("unroll") for (int s = 0; s < 4; ++s) {                                  \
        bf16x8 kf = *(const bf16x8*)(lds + KCUR + koff[n][s]);                         \
        a = __builtin_amdgcn_mfma_f32_32x32x16_bf16(kf, qf[s], a, 0, 0, 0);            \
      }                                                                                \
      __builtin_amdgcn_s_setprio(0);                                                   \
      if (t >= 2 * qt) { /* diagonal region: mask kv > qrow */                         \
        int kvb = t * 64;                                                              \
        _Pragma("unroll") for (int m = 0; m < 4; ++m)                                  \
          _Pragma("unroll") for (int c2 = 0; c2 < 4; ++c2) {                           \
            int kv = kvb + n * 32 + m * 8 + hi * 4 + c2;                               \
            if (kv > qrow) a[m * 4 + c2] = -1e30f;                                     \
          }                                                                            \
      }                                                                                \
      float u[16];                                                                     \
      _Pragma("unroll") for (int r = 0; r < 16; ++r) {                                 \
        u[r] = __builtin_amdgcn_exp2f(a[r]);                                           \
        l_run += u[r];                                                                 \
      }                                                                                \
      _Pragma("unroll") for (int hf = 0; hf < 2; ++hf) {                               \
        unsigned int A0, A1, B0, B1;                                                   \
        asm("v_cvt_pk_bf16_f32 %0, %1, %2" : "=v"(A0) : "v"(u[hf*8+0]), "v"(u[hf*8+1]));\
        asm("v_cvt_pk_bf16_f32 %0, %1, %2" : "=v"(A1) : "v"(u[hf*8+2]), "v"(u[hf*8+3]));\
        asm("v_cvt_pk_bf16_f32 %0, %1, %2" : "=v"(B0) : "v"(u[hf*8+4]), "v"(u[hf*8+5]));\
        asm("v_cvt_pk_bf16_f32 %0, %1, %2" : "=v"(B1) : "v"(u[hf*8+6]), "v"(u[hf*8+7]));\
        asm("v_permlane32_swap_b32 %0, %1" : "+v"(A0), "+v"(B0));                      \
        asm("v_permlane32_swap_b32 %0, %1" : "+v"(A1), "+v"(B1));                      \
        u32x4 pk; pk[0] = A0; pk[1] = A1; pk[2] = B0; pk[3] = B1;                      \
        pb[n * 2 + hf] = __builtin_bit_cast(bf16x8, pk);                               \
      }                                                                                \
    }                                                                                  \
    __builtin_amdgcn_s_setprio(1);                                                     \
    _Pragma("unroll") for (int dt = 0; dt < 2; ++dt) {                                 \
      _Pragma("unroll") for (int s = 0; s < 4; ++s) {                                  \
        bf16x8 vf = *(const bf16x8*)(lds + VCUR + koff[dt][s]);                        \
        zt[dt] = __builtin_amdgcn_mfma_f32_32x32x16_bf16(vf, pb[s], zt[dt], 0, 0, 0);  \
      }                                                                                \
    }                                                                                  \
    __builtin_amdgcn_s_setprio(0);                                                     \
  } while (0)

#pragma unroll 1
  for (int t = 0; t < ntiles; ++t) {
    if ((t & 1) == 0) {
      ATTN_TILE(0, 16384, 8192, 24576);
    } else {
      ATTN_TILE(8192, 24576, 0, 16384);
    }
  }
#undef ATTN_TILE

  // epilogue
  l_run += __shfl_xor(l_run, 32);
  float inv = __builtin_amdgcn_rcpf(l_run);
  unsigned short* Zrow = Z + (size_t)(b * T_ + qrow) * D_ + h * DH_;
#pragma unroll
  for (int dt = 0; dt < 2; ++dt)
#pragma unroll
    for (int m = 0; m < 4; ++m) {
      ushort4 o;
      o.x = f2bf(zt[dt][m * 4 + 0] * inv);
      o.y = f2bf(zt[dt][m * 4 + 1] * inv);
      o.z = f2bf(zt[dt][m * 4 + 2] * inv);
      o.w = f2bf(zt[dt][m * 4 + 3] * inv);
      *(ushort4*)(Zrow + dt * 32 + m * 8 + hi * 4) = o;  // d = 32dt + 8m + 4hi + c
    }
}

// ---------------------------------------------------------------- launcher
extern "C" void kernel_launch(void* const* d_in, const int* in_sizes, int n_in,
                              void* d_out, int out_size, void* d_ws, size_t ws_size,
                              hipStream_t stream) {
  (void)in_sizes; (void)n_in; (void)out_size; (void)ws_size;
  const float* x  = (const float*)d_in[0];
  const float* wq = (const float*)d_in[1];
  const float* bq = (const float*)d_in[2];
  const float* wk = (const float*)d_in[3];
  const float* bk = (const float*)d_in[4];
  const float* wv = (const float*)d_in[5];
  const float* bv = (const float*)d_in[6];
  const float* wo = (const float*)d_in[7];
  const float* bo = (const float*)d_in[8];

  char* ws = (char*)d_ws;
  const size_t XB = (size_t)M_ * D_ * 2;   // 12.58 MB
  const size_t WB = (size_t)D_ * D_ * 2;   // 1.18 MB
  unsigned short* xb  = (unsigned short*)(ws);
  unsigned short* wqb = (unsigned short*)(ws + XB);
  unsigned short* wkb = (unsigned short*)(ws + XB + WB);
  unsigned short* wvb = (unsigned short*)(ws + XB + 2 * WB);
  unsigned short* wob = (unsigned short*)(ws + XB + 3 * WB);
  unsigned short* Qb  = (unsigned short*)(ws + XB + 4 * WB);
  unsigned short* Kb  = (unsigned short*)(ws + XB + 4 * WB + XB);
  unsigned short* VTb = (unsigned short*)(ws + XB + 4 * WB + 2 * XB);
  unsigned short* Zb  = xb;  // alias: x dead after projections

  const float SCALE_Q = 0.125f * 1.44269504f;  // fold 1/sqrt(64) and log2(e) into Q

  cvt_kernel<<<dim3(1024, 5), 256, 0, stream>>>(x, wq, wk, wv, wo, xb, wqb, wkb, wvb, wob);
  // fused QKV projections; Q prescaled; V (y==2) writes V^T layout. flat grid 1152.
  gemm_kernel<<<dim3(8 * 8 * 18), 256, 0, stream>>>(
      xb, wqb, wkb, wvb, bq, bk, bv, Qb, Kb, VTb, SCALE_Q, 1.0f, 1.0f, M_, D_, D_, 1);
  // attn: 768 blocks = 48 heads x 16 q-tiles (q=128 each), desc-qt within XCD
  attn_kernel<<<dim3(768), 256, 0, stream>>>(Qb, Kb, VTb, Zb);
  // out projection -> fp32 d_out. flat grid 384.
  gemm_kernel<<<dim3(8 * 8 * 6), 256, 0, stream>>>(
      Zb, wob, wob, wob, bo, bo, bo, d_out, d_out, d_out, 1.0f, 1.0f, 1.0f, M_, D_, D_, 0);
}